// Round 9
// baseline (124.328 us; speedup 1.0000x reference)
//
#include <hip/hip_runtime.h>
#include <cstdint>
#include <cstddef>

// Problem sizes (fixed by the reference)
#define MDIM 16384   // N_INPUT
#define CDIM 4096    // NUM_CENTERS
#define DDIM 256     // DIM
#define KDIM 512     // folded K elements; fp4 -> 256 bytes per row
#define KB   256     // row bytes (fp4)
#define NBN  32      // CDIM/128 partial slabs

typedef float f32x4  __attribute__((ext_vector_type(4)));
typedef int   i32x4v __attribute__((ext_vector_type(4)));
typedef int   i32x8v __attribute__((ext_vector_type(8)));

// e2m1 (OCP MXFP4) quantize, round-to-nearest: grid {0,.5,1,1.5,2,3,4,6}
__device__ __forceinline__ unsigned q4(float v) {
    unsigned s = (__builtin_bit_cast(unsigned, v) >> 31) << 3;
    float a = fabsf(v);
    unsigned c = (unsigned)(a >= 0.25f) + (a >= 0.75f) + (a >= 1.25f)
               + (a >= 1.75f) + (a >= 2.5f) + (a >= 3.5f) + (a >= 5.0f);
    return s | c;
}
__device__ __forceinline__ unsigned pack8(const float* v) {  // 8 vals -> 8 nibbles
    unsigned w = 0;
    #pragma unroll
    for (int i = 0; i < 8; ++i) w |= q4(v[i]) << (4 * i);
    return w;
}

// ---------------------------------------------------------------------------
// prep (fp4): A'[n] = [ x (256 fp4) | x^2/8 (256 fp4) ]       row = 256 B
//             B'[c] = [ -2*c*inv (256 fp4) | inv*8 (256 fp4) ]
//             constc[c] = sum_d c^2*inv (fp32).  Scales undone by MFMA E8M0.
// ---------------------------------------------------------------------------
__global__ __launch_bounds__(256) void prep(
    const float* __restrict__ x, const float* __restrict__ centers,
    const float* __restrict__ sigmas,
    unsigned char* __restrict__ Ap, unsigned char* __restrict__ Bp,
    float* __restrict__ constc) {
    int b = blockIdx.x, tid = threadIdx.x;
    if (b < 2048) {
        int idx8 = b * 256 + tid;                 // over MDIM*DDIM/8
        int n = idx8 >> 5, d8 = idx8 & 31;
        float v[8], v2[8];
        *(float4*)(v)     = ((const float4*)x)[idx8 * 2];
        *(float4*)(v + 4) = ((const float4*)x)[idx8 * 2 + 1];
        #pragma unroll
        for (int i = 0; i < 8; ++i) v2[i] = v[i] * v[i] * 0.125f;  // x^2/8
        *(unsigned*)(Ap + (size_t)n * KB + d8 * 4)       = pack8(v);
        *(unsigned*)(Ap + (size_t)n * KB + 128 + d8 * 4) = pack8(v2);
    } else {
        int gid8 = (b - 2048) * 256 + tid;        // over CDIM*DDIM/8
        int c = gid8 >> 5, d8 = gid8 & 31;
        float cv[8], sv[8], cr[8], iv[8];
        *(float4*)(cv)     = ((const float4*)centers)[gid8 * 2];
        *(float4*)(cv + 4) = ((const float4*)centers)[gid8 * 2 + 1];
        *(float4*)(sv)     = ((const float4*)sigmas)[gid8 * 2];
        *(float4*)(sv + 4) = ((const float4*)sigmas)[gid8 * 2 + 1];
        float t = 0.0f;
        #pragma unroll
        for (int i = 0; i < 8; ++i) {
            float inv = 1.0f / (2.0f * sv[i] * sv[i]);
            cr[i] = -2.0f * cv[i] * inv;
            iv[i] = inv * 8.0f;                   // inv*8 (undone by 2^-3)
            t += cv[i] * cv[i] * inv;
        }
        *(unsigned*)(Bp + (size_t)c * KB + d8 * 4)       = pack8(cr);
        *(unsigned*)(Bp + (size_t)c * KB + 128 + d8 * 4) = pack8(iv);
        #pragma unroll
        for (int m = 16; m; m >>= 1) t += __shfl_xor(t, m, 64);  // 32-lane groups
        if ((tid & 31) == 0) constc[c] = t;
    }
}

// ---------------------------------------------------------------------------
// Fused MX-fp4 GEMM + exp + weighted C-reduction.  (R23 = R22 + skip-exp.)
// d2 = A' B'^T + constc ; part[bn][m] = sum_{n in bn-slab} exp(-d2)*w[n]
//
// R22 (atomic tail -> contention-free partial stores) broke the 8-round
// 45-µs pin: gemm fell out of the top-5 (<45 µs; total 114.8, session
// best).  R23 re-applies R21's wave-uniform skip-exp epilogue, whose
// VALU saving was counter-verified (VALUBusy 44->17%) but which regressed
// in R21 ONLY through the atomic-thrash confound (WRITE_SIZE 8.2->66.7 MB
// = faster epilogue -> denser atomic bursts -> L2 line ping-pong).  With
// private stores that coupling is gone.  Skip math: quad min4 + __any
// vote vs thr_j = 60*ln2 - constc; d2 on N(0,1) data has mean ~85,
// std ~9.5 -> ~all exp(-d2) < 1e-14; worst-case total score error
// < 1e-12 for ANY input (adversarial inputs just run the slow path).
// Slow path: raw v_exp_f32 (ocml exp2f adds range-check VALU).
// Base: single barrier, A direct->VGPR, two stride-128 LDS buffers
// (0 conflicts), natural 2D grid, launch_bounds(256,3), minimal tail.
// ---------------------------------------------------------------------------
#define AS1 __attribute__((address_space(1)))
#define AS3 __attribute__((address_space(3)))

__global__ __launch_bounds__(256, 3) void gemm_fused(
    const unsigned char* __restrict__ A, const unsigned char* __restrict__ B,
    const float* __restrict__ constc, const float* __restrict__ w,
    float* __restrict__ part) {

    __shared__ unsigned char Bs0[128 * 128];   // K-half 0 (bytes 0..127)
    __shared__ unsigned char Bs1[128 * 128];   // K-half 1 (bytes 128..255)

    const int tid  = threadIdx.x;
    const int wave = tid >> 6;
    const int lane = tid & 63;
    const int quad = lane >> 4;      // 0..3
    const int l16  = lane & 15;

    const int bn = blockIdx.x;       // 0..31   (C blocks of 128)
    const int bm = blockIdx.y;       // 0..127  (M blocks of 128)

    const int wave_m = wave * 32;    // wave's 32 M-rows

    // ---- stage B (conflict-free pattern): slab = 8 rows x 128 B per buffer;
    // lane -> row (lane>>3), chunk (lane&7); source pre-swizzled chunk^row.
    const unsigned char* Bbase = B + (size_t)(bn * 128) * KB;
    {
        const int st_row = lane >> 3;                  // 0..7
        const int st_k   = ((lane & 7) ^ st_row) * 16; // swizzled byte off
        #pragma unroll
        for (int c = 0; c < 4; ++c) {
            int slab = wave * 4 + c;                   // 0..15
            const unsigned char* g0 = Bbase + (size_t)(slab * 8 + st_row) * KB + st_k;
            __builtin_amdgcn_global_load_lds((const AS1 void*)g0,
                (AS3 void*)(Bs0 + slab * 1024), 16, 0, 0);
            const unsigned char* g1 = Bbase + (size_t)(slab * 8 + st_row) * KB + 128 + st_k;
            __builtin_amdgcn_global_load_lds((const AS1 void*)g1,
                (AS3 void*)(Bs1 + slab * 1024), 16, 0, 0);
        }
    }

    // ---- epilogue constants prefetched (hide under the same vmcnt drain):
    // wj = w[ng]; cjl = -log2e*constc; thr = 60*ln2 - constc (skip threshold).
    const float NEG_LOG2E = -1.4426950408889634f;
    float wj[8], cjl[8], thr[8];
    #pragma unroll
    for (int j = 0; j < 8; ++j) {
        int ng = bn * 128 + j * 16 + l16;
        float cc = constc[ng];
        wj[j]  = w[ng];
        cjl[j] = NEG_LOG2E * cc;
        thr[j] = 41.5888308336f - cc;       // 60*ln2 - constc
    }

    // ---- A fragments direct global->VGPR (wave-private; L2/L3-served).
    // row = bm*128 + wave_m + i*16 + l16; byte = kh*64 + quad*16.
    const unsigned char* Abase = A + (size_t)(bm * 128 + wave_m) * KB;
    i32x4v af[2][4];
    #pragma unroll
    for (int i = 0; i < 2; ++i)
        #pragma unroll
        for (int kh = 0; kh < 4; ++kh)
            af[i][kh] = *(const i32x4v*)(Abase + (size_t)(i * 16 + l16) * KB
                                         + kh * 64 + quad * 16);

    __syncthreads();   // single drain: B in LDS, af + constants in regs

    f32x4 acc[2][8] = {};
    const int rsw = l16 & 7;
    #pragma unroll
    for (int kh = 0; kh < 4; ++kh) {          // 4 K-windows of 128 elems
        const int sA = (kh & 2) ? 0x82828282 : 0x7F7F7F7F;   // 2^3 : 2^0
        const int sB = (kh & 2) ? 0x7C7C7C7C : 0x7F7F7F7F;   // 2^-3 : 2^0
        const unsigned char* Bbuf = (kh >> 1) ? Bs1 : Bs0;
        const int sl = ((((kh & 1) * 4 + quad) ^ rsw) * 16);
        #pragma unroll
        for (int j = 0; j < 8; ++j) {
            i32x4v lo = *(const i32x4v*)(Bbuf + (j * 16 + l16) * 128 + sl);
            i32x8v bf = __builtin_shufflevector(lo, lo, 0, 1, 2, 3, -1, -1, -1, -1);
            #pragma unroll
            for (int i = 0; i < 2; ++i) {
                i32x8v a8 = __builtin_shufflevector(af[i][kh], af[i][kh],
                                                    0, 1, 2, 3, -1, -1, -1, -1);
                acc[i][j] = __builtin_amdgcn_mfma_scale_f32_16x16x128_f8f6f4(
                    a8, bf, acc[i][j],
                    4 /*cbsz: fp4 e2m1*/, 4 /*blgp: fp4 e2m1*/,
                    0, sA, 0, sB);
            }
        }
    }

    // Epilogue with wave-uniform exp skip.
    // C/D layout (16x16): col = l16 (=n), row = quad*4 + reg (=m).
    // Quad (i,j) contributes iff any lane has acc < thr_j (d2 < 60*ln2).
    float rowsum[2][4];
    #pragma unroll
    for (int i = 0; i < 2; ++i)
        #pragma unroll
        for (int r = 0; r < 4; ++r) rowsum[i][r] = 0.0f;

    #pragma unroll
    for (int j = 0; j < 8; ++j) {
        #pragma unroll
        for (int i = 0; i < 2; ++i) {
            float mn = fminf(fminf(acc[i][j][0], acc[i][j][1]),
                             fminf(acc[i][j][2], acc[i][j][3]));
            if (__any(mn < thr[j])) {
                #pragma unroll
                for (int r = 0; r < 4; ++r) {
                    float u = fmaf(acc[i][j][r], NEG_LOG2E, cjl[j]);
                    float t;
                    asm("v_exp_f32 %0, %1" : "=v"(t) : "v"(u));
                    rowsum[i][r] = fmaf(t, wj[j], rowsum[i][r]);
                }
            }
        }
    }

    #pragma unroll
    for (int mask = 1; mask < 16; mask <<= 1)
        #pragma unroll
        for (int i = 0; i < 2; ++i)
            #pragma unroll
            for (int r = 0; r < 4; ++r)
                rowsum[i][r] += __shfl_xor(rowsum[i][r], mask, 64);

    // Contention-free partial store: part[bn][mg].  Per block: 128 plain
    // contiguous dword stores (8 cache lines), no RMW, no cross-block sharing.
    if (l16 == 0) {
        float* prow = part + (size_t)bn * MDIM + bm * 128 + wave_m;
        #pragma unroll
        for (int i = 0; i < 2; ++i)
            #pragma unroll
            for (int r = 0; r < 4; ++r)
                prow[i * 16 + quad * 4 + r] = rowsum[i][r];
    }
}

// ---------------------------------------------------------------------------
// finalize: out[n] = sigmoid(sum_bn part[bn][n] + b)
// ---------------------------------------------------------------------------
__global__ __launch_bounds__(256) void finalize(
    const float* __restrict__ part, const float* __restrict__ b,
    float* __restrict__ out) {
    int n = blockIdx.x * 256 + threadIdx.x;
    float s = b[0];
    #pragma unroll
    for (int bn = 0; bn < NBN; ++bn)
        s += part[(size_t)bn * MDIM + n];      // coalesced across threads
    out[n] = 1.0f / (1.0f + exp2f(-1.4426950408889634f * s));
}

extern "C" void kernel_launch(void* const* d_in, const int* in_sizes, int n_in,
                              void* d_out, int out_size, void* d_ws, size_t ws_size,
                              hipStream_t stream) {
    const float* x       = (const float*)d_in[0];
    const float* centers = (const float*)d_in[1];
    const float* sigmas  = (const float*)d_in[2];
    const float* w_lin   = (const float*)d_in[3];
    const float* b_lin   = (const float*)d_in[4];
    float* out = (float*)d_out;

    char* ws = (char*)d_ws;
    unsigned char* Ap = (unsigned char*)ws;                       // 4 MB
    unsigned char* Bp = (unsigned char*)(ws + (size_t)MDIM * KB); // 1 MB
    float* cc   = (float*)(ws + (size_t)MDIM * KB + (size_t)CDIM * KB); // 16 KB
    float* part = (float*)((char*)cc + CDIM * sizeof(float));     // 2 MB

    prep<<<dim3(2048 + 512), dim3(256), 0, stream>>>(
        x, centers, sigmas, Ap, Bp, cc);
    gemm_fused<<<dim3(CDIM / 128, MDIM / 128), dim3(256), 0, stream>>>(
        Ap, Bp, cc, w_lin, part);
    finalize<<<dim3(MDIM / 256), dim3(256), 0, stream>>>(part, b_lin, out);
}

// Round 10
// 113.531 us; speedup vs baseline: 1.0951x; 1.0951x over previous
//
#include <hip/hip_runtime.h>
#include <cstdint>
#include <cstddef>

// Problem sizes (fixed by the reference)
#define MDIM 16384   // N_INPUT
#define CDIM 4096    // NUM_CENTERS
#define DDIM 256     // DIM
#define KDIM 512     // folded K elements; fp4 -> 256 bytes per row
#define KB   256     // row bytes (fp4)
#define NBN  32      // CDIM/128 partial slabs

typedef float f32x4  __attribute__((ext_vector_type(4)));
typedef int   i32x4v __attribute__((ext_vector_type(4)));
typedef int   i32x8v __attribute__((ext_vector_type(8)));

// e2m1 (OCP MXFP4) quantize, round-to-nearest: grid {0,.5,1,1.5,2,3,4,6}
__device__ __forceinline__ unsigned q4(float v) {
    unsigned s = (__builtin_bit_cast(unsigned, v) >> 31) << 3;
    float a = fabsf(v);
    unsigned c = (unsigned)(a >= 0.25f) + (a >= 0.75f) + (a >= 1.25f)
               + (a >= 1.75f) + (a >= 2.5f) + (a >= 3.5f) + (a >= 5.0f);
    return s | c;
}
__device__ __forceinline__ unsigned pack8(const float* v) {  // 8 vals -> 8 nibbles
    unsigned w = 0;
    #pragma unroll
    for (int i = 0; i < 8; ++i) w |= q4(v[i]) << (4 * i);
    return w;
}

// ---------------------------------------------------------------------------
// prep (fp4): A'[n] = [ x (256 fp4) | x^2/8 (256 fp4) ]       row = 256 B
//             B'[c] = [ -2*c*inv (256 fp4) | inv*8 (256 fp4) ]
//             constc[c] = sum_d c^2*inv (fp32).  Scales undone by MFMA E8M0.
// ---------------------------------------------------------------------------
__global__ __launch_bounds__(256) void prep(
    const float* __restrict__ x, const float* __restrict__ centers,
    const float* __restrict__ sigmas,
    unsigned char* __restrict__ Ap, unsigned char* __restrict__ Bp,
    float* __restrict__ constc) {
    int b = blockIdx.x, tid = threadIdx.x;
    if (b < 2048) {
        int idx8 = b * 256 + tid;                 // over MDIM*DDIM/8
        int n = idx8 >> 5, d8 = idx8 & 31;
        float v[8], v2[8];
        *(float4*)(v)     = ((const float4*)x)[idx8 * 2];
        *(float4*)(v + 4) = ((const float4*)x)[idx8 * 2 + 1];
        #pragma unroll
        for (int i = 0; i < 8; ++i) v2[i] = v[i] * v[i] * 0.125f;  // x^2/8
        *(unsigned*)(Ap + (size_t)n * KB + d8 * 4)       = pack8(v);
        *(unsigned*)(Ap + (size_t)n * KB + 128 + d8 * 4) = pack8(v2);
    } else {
        int gid8 = (b - 2048) * 256 + tid;        // over CDIM*DDIM/8
        int c = gid8 >> 5, d8 = gid8 & 31;
        float cv[8], sv[8], cr[8], iv[8];
        *(float4*)(cv)     = ((const float4*)centers)[gid8 * 2];
        *(float4*)(cv + 4) = ((const float4*)centers)[gid8 * 2 + 1];
        *(float4*)(sv)     = ((const float4*)sigmas)[gid8 * 2];
        *(float4*)(sv + 4) = ((const float4*)sigmas)[gid8 * 2 + 1];
        float t = 0.0f;
        #pragma unroll
        for (int i = 0; i < 8; ++i) {
            float inv = 1.0f / (2.0f * sv[i] * sv[i]);
            cr[i] = -2.0f * cv[i] * inv;
            iv[i] = inv * 8.0f;                   // inv*8 (undone by 2^-3)
            t += cv[i] * cv[i] * inv;
        }
        *(unsigned*)(Bp + (size_t)c * KB + d8 * 4)       = pack8(cr);
        *(unsigned*)(Bp + (size_t)c * KB + 128 + d8 * 4) = pack8(iv);
        #pragma unroll
        for (int m = 16; m; m >>= 1) t += __shfl_xor(t, m, 64);  // 32-lane groups
        if ((tid & 31) == 0) constc[c] = t;
    }
}

// ---------------------------------------------------------------------------
// Fused MX-fp4 GEMM + exp + weighted C-reduction.  (R24 = R22 + occupancy 4.)
// d2 = A' B'^T + constc ; part[bn][m] = sum_{n in bn-slab} exp(-d2)*w[n]
//
// Session ledger: R22 (this structure at launch_bounds(256,3)) = 114.8 µs
// session best; gemm out of top-5 (<45 µs) for the first time after the
// atomicAdd tail was replaced with contention-free partial stores.
// Skip-exp epilogue: convicted by two A/Bs (R20->R21 +10.6, R22->R23
// +9.5 µs) — exec-mask branching costs more than the saved VALU; plain
// exp2f epilogue is ~5 µs chip-wide (64 elems x 12 cyc per wave).  Note:
// TCC FETCH/WRITE_SIZE are device-window counters — concurrent poison
// fill traffic leaks into gemm's numbers; don't over-read them.
// R24 single change: __launch_bounds__(256,4) — 4th resident block/CU
// (VGPR 84 <= 128, LDS 4x32=128 <= 160 KB) to overlap one more
// stage->drain chain.  This was R12's original setting; R16 dropped it
// to 3 un-A/B'd.
// Base: single barrier, A direct->VGPR, two stride-128 LDS buffers
// (0 conflicts), natural 2D grid, minimal tail, separate finalize.
// ---------------------------------------------------------------------------
#define AS1 __attribute__((address_space(1)))
#define AS3 __attribute__((address_space(3)))

__global__ __launch_bounds__(256, 4) void gemm_fused(
    const unsigned char* __restrict__ A, const unsigned char* __restrict__ B,
    const float* __restrict__ constc, const float* __restrict__ w,
    float* __restrict__ part) {

    __shared__ unsigned char Bs0[128 * 128];   // K-half 0 (bytes 0..127)
    __shared__ unsigned char Bs1[128 * 128];   // K-half 1 (bytes 128..255)

    const int tid  = threadIdx.x;
    const int wave = tid >> 6;
    const int lane = tid & 63;
    const int quad = lane >> 4;      // 0..3
    const int l16  = lane & 15;

    const int bn = blockIdx.x;       // 0..31   (C blocks of 128)
    const int bm = blockIdx.y;       // 0..127  (M blocks of 128)

    const int wave_m = wave * 32;    // wave's 32 M-rows

    // ---- stage B (conflict-free pattern): slab = 8 rows x 128 B per buffer;
    // lane -> row (lane>>3), chunk (lane&7); source pre-swizzled chunk^row.
    const unsigned char* Bbase = B + (size_t)(bn * 128) * KB;
    {
        const int st_row = lane >> 3;                  // 0..7
        const int st_k   = ((lane & 7) ^ st_row) * 16; // swizzled byte off
        #pragma unroll
        for (int c = 0; c < 4; ++c) {
            int slab = wave * 4 + c;                   // 0..15
            const unsigned char* g0 = Bbase + (size_t)(slab * 8 + st_row) * KB + st_k;
            __builtin_amdgcn_global_load_lds((const AS1 void*)g0,
                (AS3 void*)(Bs0 + slab * 1024), 16, 0, 0);
            const unsigned char* g1 = Bbase + (size_t)(slab * 8 + st_row) * KB + 128 + st_k;
            __builtin_amdgcn_global_load_lds((const AS1 void*)g1,
                (AS3 void*)(Bs1 + slab * 1024), 16, 0, 0);
        }
    }

    // ---- epilogue constants prefetched (hide under the same vmcnt drain).
    const float NEG_LOG2E = -1.4426950408889634f;
    float wj[8], cjl[8];
    #pragma unroll
    for (int j = 0; j < 8; ++j) {
        int ng = bn * 128 + j * 16 + l16;
        wj[j]  = w[ng];
        cjl[j] = NEG_LOG2E * constc[ng];
    }

    // ---- A fragments direct global->VGPR (wave-private; L2/L3-served).
    // row = bm*128 + wave_m + i*16 + l16; byte = kh*64 + quad*16.
    const unsigned char* Abase = A + (size_t)(bm * 128 + wave_m) * KB;
    i32x4v af[2][4];
    #pragma unroll
    for (int i = 0; i < 2; ++i)
        #pragma unroll
        for (int kh = 0; kh < 4; ++kh)
            af[i][kh] = *(const i32x4v*)(Abase + (size_t)(i * 16 + l16) * KB
                                         + kh * 64 + quad * 16);

    __syncthreads();   // single drain: B in LDS, af + constants in regs

    f32x4 acc[2][8] = {};
    const int rsw = l16 & 7;
    #pragma unroll
    for (int kh = 0; kh < 4; ++kh) {          // 4 K-windows of 128 elems
        const int sA = (kh & 2) ? 0x82828282 : 0x7F7F7F7F;   // 2^3 : 2^0
        const int sB = (kh & 2) ? 0x7C7C7C7C : 0x7F7F7F7F;   // 2^-3 : 2^0
        const unsigned char* Bbuf = (kh >> 1) ? Bs1 : Bs0;
        const int sl = ((((kh & 1) * 4 + quad) ^ rsw) * 16);
        #pragma unroll
        for (int j = 0; j < 8; ++j) {
            i32x4v lo = *(const i32x4v*)(Bbuf + (j * 16 + l16) * 128 + sl);
            i32x8v bf = __builtin_shufflevector(lo, lo, 0, 1, 2, 3, -1, -1, -1, -1);
            #pragma unroll
            for (int i = 0; i < 2; ++i) {
                i32x8v a8 = __builtin_shufflevector(af[i][kh], af[i][kh],
                                                    0, 1, 2, 3, -1, -1, -1, -1);
                acc[i][j] = __builtin_amdgcn_mfma_scale_f32_16x16x128_f8f6f4(
                    a8, bf, acc[i][j],
                    4 /*cbsz: fp4 e2m1*/, 4 /*blgp: fp4 e2m1*/,
                    0, sA, 0, sB);
            }
        }
    }

    // Epilogue.  C/D layout (16x16): col = l16 (=n), row = quad*4 + reg (=m).
    float rowsum[2][4];
    #pragma unroll
    for (int i = 0; i < 2; ++i)
        #pragma unroll
        for (int r = 0; r < 4; ++r) rowsum[i][r] = 0.0f;

    #pragma unroll
    for (int j = 0; j < 8; ++j) {
        #pragma unroll
        for (int i = 0; i < 2; ++i)
            #pragma unroll
            for (int r = 0; r < 4; ++r)
                rowsum[i][r] += exp2f(fmaf(acc[i][j][r], NEG_LOG2E, cjl[j])) * wj[j];
    }

    #pragma unroll
    for (int mask = 1; mask < 16; mask <<= 1)
        #pragma unroll
        for (int i = 0; i < 2; ++i)
            #pragma unroll
            for (int r = 0; r < 4; ++r)
                rowsum[i][r] += __shfl_xor(rowsum[i][r], mask, 64);

    // Contention-free partial store: part[bn][mg].  Per block: 128 plain
    // contiguous dword stores (8 cache lines), no RMW, no cross-block sharing.
    if (l16 == 0) {
        float* prow = part + (size_t)bn * MDIM + bm * 128 + wave_m;
        #pragma unroll
        for (int i = 0; i < 2; ++i)
            #pragma unroll
            for (int r = 0; r < 4; ++r)
                prow[i * 16 + quad * 4 + r] = rowsum[i][r];
    }
}

// ---------------------------------------------------------------------------
// finalize: out[n] = sigmoid(sum_bn part[bn][n] + b)
// ---------------------------------------------------------------------------
__global__ __launch_bounds__(256) void finalize(
    const float* __restrict__ part, const float* __restrict__ b,
    float* __restrict__ out) {
    int n = blockIdx.x * 256 + threadIdx.x;
    float s = b[0];
    #pragma unroll
    for (int bn = 0; bn < NBN; ++bn)
        s += part[(size_t)bn * MDIM + n];      // coalesced across threads
    out[n] = 1.0f / (1.0f + exp2f(-1.4426950408889634f * s));
}

extern "C" void kernel_launch(void* const* d_in, const int* in_sizes, int n_in,
                              void* d_out, int out_size, void* d_ws, size_t ws_size,
                              hipStream_t stream) {
    const float* x       = (const float*)d_in[0];
    const float* centers = (const float*)d_in[1];
    const float* sigmas  = (const float*)d_in[2];
    const float* w_lin   = (const float*)d_in[3];
    const float* b_lin   = (const float*)d_in[4];
    float* out = (float*)d_out;

    char* ws = (char*)d_ws;
    unsigned char* Ap = (unsigned char*)ws;                       // 4 MB
    unsigned char* Bp = (unsigned char*)(ws + (size_t)MDIM * KB); // 1 MB
    float* cc   = (float*)(ws + (size_t)MDIM * KB + (size_t)CDIM * KB); // 16 KB
    float* part = (float*)((char*)cc + CDIM * sizeof(float));     // 2 MB

    prep<<<dim3(2048 + 512), dim3(256), 0, stream>>>(
        x, centers, sigmas, Ap, Bp, cc);
    gemm_fused<<<dim3(CDIM / 128, MDIM / 128), dim3(256), 0, stream>>>(
        Ap, Bp, cc, w_lin, part);
    finalize<<<dim3(MDIM / 256), dim3(256), 0, stream>>>(part, b_lin, out);
}